// Round 1
// baseline (180.509 us; speedup 1.0000x reference)
//
#include <hip/hip_runtime.h>
#include <math.h>

#define NB 16
#define CF 64
#define LL 16384
#define GG 8
#define DI 16
#define DS 16
#define NH 2
#define HD 8
#define CONVD 48
#define DPROJ 66
#define SEG 256
#define NSEG 64
#define NCHK 64
#define CHUNK 64

static constexpr size_t OFF_GT = 0;
static constexpr size_t OFF_XR = OFF_GT + (size_t)NB*LL*GG;
static constexpr size_t OFF_B  = OFF_XR + (size_t)NB*LL*DI;
static constexpr size_t OFF_C  = OFF_B  + (size_t)NB*LL*DS;
static constexpr size_t OFF_DT = OFF_C  + (size_t)NB*LL*DS;
static constexpr size_t OFF_DE = OFF_DT + (size_t)NB*LL*NH;
static constexpr size_t OFF_YL = OFF_DE + (size_t)NB*LL*NH;
static constexpr size_t OFF_CA = OFF_YL + (size_t)NB*LL*DI;
static constexpr size_t OFF_U  = OFF_CA + (size_t)NB*LL*NH;
static constexpr size_t OFF_AS = OFF_U  + (size_t)NB*NSEG*256;
static constexpr size_t OFF_HI = OFF_AS + (size_t)NB*NSEG*NH;
static constexpr size_t WS_FLOATS = OFF_HI + (size_t)NB*NSEG*256;

__device__ __forceinline__ float siluf(float v){ return v / (1.f + __expf(-v)); }
__device__ __forceinline__ float softplusf(float v){ return v > 20.f ? v : log1pf(__expf(v)); }

__device__ __forceinline__ void load16(float* d, const float* p){
    float4 a = ((const float4*)p)[0];
    float4 b = ((const float4*)p)[1];
    float4 c = ((const float4*)p)[2];
    float4 e = ((const float4*)p)[3];
    d[0]=a.x; d[1]=a.y; d[2]=a.z; d[3]=a.w;
    d[4]=b.x; d[5]=b.y; d[6]=b.z; d[7]=b.w;
    d[8]=c.x; d[9]=c.y; d[10]=c.z; d[11]=c.w;
    d[12]=e.x; d[13]=e.y; d[14]=e.z; d[15]=e.w;
}

// K1: tokenize + in_proj + depthwise causal conv3 + silu + dt/dec
__global__ __launch_bounds__(256, 2) void k1_front(
    const float* __restrict__ x, const float* __restrict__ tok_w, const float* __restrict__ tok_b,
    const float* __restrict__ ipw, const float* __restrict__ ipb,
    const float* __restrict__ cw, const float* __restrict__ cb,
    const float* __restrict__ A_log, const float* __restrict__ dt_bias,
    float* __restrict__ gtw, float* __restrict__ xrw, float* __restrict__ bmw,
    float* __restrict__ cmw, float* __restrict__ dtw, float* __restrict__ dew)
{
    __shared__ float s_xbc[CONVD][258];      // transposed: [ch][row], conflict-free
    __shared__ float s_tok[GG*CF];
    __shared__ float s_ipw[DPROJ*GG];
    __shared__ float s_cw[CONVD*3];
    int tid = threadIdx.x;
    int b  = blockIdx.x >> 6;
    int ck = blockIdx.x & 63;
    int t0 = ck << 8;
    for (int i = tid; i < GG*CF; i += 256) s_tok[i] = tok_w[i];
    for (int i = tid; i < DPROJ*GG; i += 256) s_ipw[i] = ipw[i];
    for (int i = tid; i < CONVD*3; i += 256) s_cw[i] = cw[i];
    __syncthreads();
    float a0 = __expf(A_log[0]), a1 = __expf(A_log[1]);
    float dtb0 = dt_bias[0], dtb1 = dt_bias[1];
    int nrows = (tid < 2) ? 2 : 1;
    for (int ri = 0; ri < nrows; ++ri) {
        int row = tid + ri*256;
        int l = t0 - 2 + row;
        if (l < 0) {                 // conv pre-padding (only chunk 0)
            #pragma unroll
            for (int ch = 0; ch < CONVD; ++ch) s_xbc[ch][row] = 0.f;
            continue;
        }
        float gacc[GG];
        #pragma unroll
        for (int g = 0; g < GG; ++g) gacc[g] = tok_b[g];
        const float* xb = x + (size_t)b*CF*LL + l;
        for (int c = 0; c < CF; ++c) {
            float xv = xb[(size_t)c*LL];
            #pragma unroll
            for (int g = 0; g < GG; ++g) gacc[g] = fmaf(xv, s_tok[g*CF + c], gacc[g]);
        }
        bool central = (l >= t0);
        size_t pb = (size_t)b*LL + l;
        if (central) {
            float4* gp = (float4*)(gtw + pb*GG);
            gp[0] = make_float4(gacc[0],gacc[1],gacc[2],gacc[3]);
            gp[1] = make_float4(gacc[4],gacc[5],gacc[6],gacc[7]);
        }
        #pragma unroll
        for (int ch = 0; ch < CONVD; ++ch) {   // zxbcdt channels 16..63
            int j = 16 + ch;
            float acc = ipb[j];
            #pragma unroll
            for (int g = 0; g < GG; ++g) acc = fmaf(gacc[g], s_ipw[j*GG + g], acc);
            s_xbc[ch][row] = acc;
        }
        if (central) {                          // dt channels 64,65
            float d0 = ipb[64], d1 = ipb[65];
            #pragma unroll
            for (int g = 0; g < GG; ++g) {
                d0 = fmaf(gacc[g], s_ipw[64*GG + g], d0);
                d1 = fmaf(gacc[g], s_ipw[65*GG + g], d1);
            }
            float dt0 = softplusf(d0 + dtb0);
            float dt1 = softplusf(d1 + dtb1);
            ((float2*)(dtw + pb*NH))[0] = make_float2(dt0, dt1);
            ((float2*)(dew + pb*NH))[0] = make_float2(__expf(-dt0*a0), __expf(-dt1*a1));
        }
    }
    __syncthreads();
    for (int ri = 0; ri < nrows; ++ri) {
        int row = tid + ri*256;
        int l = t0 - 2 + row;
        if (l < t0) continue;
        float vv[CONVD];
        #pragma unroll
        for (int ch = 0; ch < CONVD; ++ch) {
            float acc = cb[ch];
            acc = fmaf(s_xbc[ch][row-2], s_cw[ch*3+0], acc);
            acc = fmaf(s_xbc[ch][row-1], s_cw[ch*3+1], acc);
            acc = fmaf(s_xbc[ch][row  ], s_cw[ch*3+2], acc);
            vv[ch] = siluf(acc);
        }
        size_t pb = (size_t)b*LL + l;
        float4* xp = (float4*)(xrw + pb*DI);
        float4* bp = (float4*)(bmw + pb*DS);
        float4* cp = (float4*)(cmw + pb*DS);
        #pragma unroll
        for (int q = 0; q < 4; ++q) {
            xp[q] = make_float4(vv[q*4+0], vv[q*4+1], vv[q*4+2], vv[q*4+3]);
            bp[q] = make_float4(vv[16+q*4+0], vv[16+q*4+1], vv[16+q*4+2], vv[16+q*4+3]);
            cp[q] = make_float4(vv[32+q*4+0], vv[32+q*4+1], vv[32+q*4+2], vv[32+q*4+3]);
        }
    }
}

// K3: per-segment scan with h_in = 0; emits y_local, cumA, segment end state U, decay product Aseg
__global__ __launch_bounds__(256, 4) void k3_scan(
    const float* __restrict__ xrw, const float* __restrict__ bmw, const float* __restrict__ cmw,
    const float* __restrict__ dtw, const float* __restrict__ dew,
    float* __restrict__ ylw, float* __restrict__ caw, float* __restrict__ Uw, float* __restrict__ Asw)
{
    __shared__ float s_x[CHUNK*16], s_B[CHUNK*16], s_C[CHUNK*16], s_y[CHUNK*16];
    __shared__ float s_dt[CHUNK*2], s_de[CHUNK*2], s_ca[CHUNK*2];
    int tid = threadIdx.x;
    int b  = blockIdx.x >> 6;
    int sg = blockIdx.x & 63;
    int t0 = sg << 8;
    int he = tid >> 7, p = (tid >> 4) & 7, n = tid & 15;
    float h = 0.f, cA = 1.f;
    for (int c0 = 0; c0 < SEG; c0 += CHUNK) {
        size_t base = (size_t)b*LL + t0 + c0;
        ((float4*)s_x)[tid] = ((const float4*)(xrw + base*16))[tid];
        ((float4*)s_B)[tid] = ((const float4*)(bmw + base*16))[tid];
        ((float4*)s_C)[tid] = ((const float4*)(cmw + base*16))[tid];
        if (tid < 32)      ((float4*)s_dt)[tid]    = ((const float4*)(dtw + base*2))[tid];
        else if (tid < 64) ((float4*)s_de)[tid-32] = ((const float4*)(dew + base*2))[tid-32];
        __syncthreads();
        for (int tt = 0; tt < CHUNK; ++tt) {
            float a = s_de[tt*2 + he];
            float u = s_dt[tt*2 + he] * s_x[tt*16 + he*8 + p] * s_B[tt*16 + n];
            h = fmaf(a, h, u);
            cA *= a;
            float v = h * s_C[tt*16 + n];
            v += __shfl_xor(v, 1);
            v += __shfl_xor(v, 2);
            v += __shfl_xor(v, 4);
            v += __shfl_xor(v, 8);
            if (n == 0) s_y[tt*16 + he*8 + p] = v;
            if ((tid & 127) == 0) s_ca[tt*2 + he] = cA;
        }
        __syncthreads();
        ((float4*)(ylw + base*16))[tid] = ((float4*)s_y)[tid];
        if (tid < 32) ((float4*)(caw + base*2))[tid] = ((float4*)s_ca)[tid];
    }
    Uw[(size_t)blockIdx.x*256 + tid] = h;
    if ((tid & 127) == 0) Asw[blockIdx.x*NH + he] = cA;
}

// K4: inter-segment state scan (64 sequential steps)
__global__ void k4_seg(const float* __restrict__ Uw, const float* __restrict__ Asw, float* __restrict__ hiw)
{
    int b = blockIdx.x, tid = threadIdx.x, he = tid >> 7;
    float h = 0.f;
    for (int s = 0; s < NSEG; ++s) {
        size_t idx = ((size_t)(b*NSEG + s))*256 + tid;
        hiw[idx] = h;
        h = fmaf(Asw[(b*NSEG + s)*NH + he], h, Uw[idx]);
    }
}

// K5: state correction + D*x + silu(z) gate + RMSNorm + out proj + residual + detokenize
__global__ __launch_bounds__(256, 2) void k5_epi(
    const float* __restrict__ x, const float* __restrict__ gtw, const float* __restrict__ xrw,
    const float* __restrict__ cmw, const float* __restrict__ ylw, const float* __restrict__ caw,
    const float* __restrict__ hiw,
    const float* __restrict__ ipw, const float* __restrict__ ipb,
    const float* __restrict__ Dv, const float* __restrict__ norm_w,
    const float* __restrict__ out_w, const float* __restrict__ out_b,
    const float* __restrict__ dkw, const float* __restrict__ dkb,
    float* __restrict__ outp)
{
    __shared__ float s_hin[256];
    __shared__ float s_g2[256*9];       // stride 9: conflict-free
    __shared__ float s_dw[CF*GG];
    int tid = threadIdx.x;
    int b  = blockIdx.x >> 6;
    int ck = blockIdx.x & 63;
    int t0 = ck << 8;
    int t = t0 + tid;
    s_hin[tid] = hiw[((size_t)(b*NSEG + ck))*256 + tid];
    for (int i = tid; i < CF*GG; i += 256) s_dw[i] = dkw[i];
    __syncthreads();
    size_t pb = (size_t)b*LL + t;
    float gv[8];
    {
        float4 g0 = ((const float4*)(gtw + pb*GG))[0];
        float4 g1 = ((const float4*)(gtw + pb*GG))[1];
        gv[0]=g0.x; gv[1]=g0.y; gv[2]=g0.z; gv[3]=g0.w;
        gv[4]=g1.x; gv[5]=g1.y; gv[6]=g1.z; gv[7]=g1.w;
    }
    float Cv[16], ylv[16], xrv[16];
    load16(Cv,  cmw + pb*16);
    load16(ylv, ylw + pb*16);
    load16(xrv, xrw + pb*16);
    float2 ca = ((const float2*)(caw + pb*NH))[0];
    float D0 = Dv[0], D1 = Dv[1];
    float vv[16]; float ss = 0.f;
    #pragma unroll
    for (int hp = 0; hp < 16; ++hp) {
        int heL = hp >> 3, pL = hp & 7;
        float dot = 0.f;
        #pragma unroll
        for (int nn = 0; nn < 16; ++nn) dot = fmaf(Cv[nn], s_hin[heL*128 + pL*16 + nn], dot);
        float zz = ipb[hp];
        #pragma unroll
        for (int g = 0; g < GG; ++g) zz = fmaf(gv[g], ipw[hp*GG + g], zz);
        float y = ylv[hp] + (heL ? ca.y : ca.x) * dot + (heL ? D1 : D0) * xrv[hp];
        float w = y * siluf(zz);
        vv[hp] = w;
        ss = fmaf(w, w, ss);
    }
    float r = rsqrtf(ss * (1.f/16.f) + 1e-5f);
    #pragma unroll
    for (int hp = 0; hp < 16; ++hp) vv[hp] *= r * norm_w[hp];
    #pragma unroll
    for (int g = 0; g < GG; ++g) {
        float acc = out_b[g] + gv[g];
        #pragma unroll
        for (int hp = 0; hp < 16; ++hp) acc = fmaf(vv[hp], out_w[g*DI + hp], acc);
        s_g2[tid*9 + g] = acc;
    }
    __syncthreads();
    const float* xb = x + (size_t)b*CF*LL + t0;
    float* ob = outp + (size_t)b*CF*LL + t0;
    for (int c = 0; c < CF; ++c) {
        float acc = xb[(size_t)c*LL + tid] + dkb[c];
        #pragma unroll
        for (int g = 0; g < GG; ++g) acc = fmaf(s_g2[tid*9 + g], s_dw[c*GG + g], acc);
        ob[(size_t)c*LL + tid] = acc;
    }
}

extern "C" void kernel_launch(void* const* d_in, const int* in_sizes, int n_in,
                              void* d_out, int out_size, void* d_ws, size_t ws_size,
                              hipStream_t stream) {
    const float* x       = (const float*)d_in[0];
    const float* tok_w   = (const float*)d_in[1];
    const float* tok_b   = (const float*)d_in[2];
    const float* detok_w = (const float*)d_in[3];
    const float* detok_b = (const float*)d_in[4];
    const float* ipw     = (const float*)d_in[5];
    const float* ipb     = (const float*)d_in[6];
    const float* cw      = (const float*)d_in[7];
    const float* cb      = (const float*)d_in[8];
    const float* A_log   = (const float*)d_in[9];
    const float* Dv      = (const float*)d_in[10];
    const float* dt_bias = (const float*)d_in[11];
    const float* norm_w  = (const float*)d_in[12];
    const float* out_w   = (const float*)d_in[13];
    const float* out_b   = (const float*)d_in[14];
    float* ws = (float*)d_ws;
    float* outp = (float*)d_out;

    if (ws_size < WS_FLOATS * sizeof(float)) return;  // workspace guard (fails validation loudly)

    k1_front<<<NB*NCHK, 256, 0, stream>>>(x, tok_w, tok_b, ipw, ipb, cw, cb, A_log, dt_bias,
        ws+OFF_GT, ws+OFF_XR, ws+OFF_B, ws+OFF_C, ws+OFF_DT, ws+OFF_DE);
    k3_scan<<<NB*NSEG, 256, 0, stream>>>(ws+OFF_XR, ws+OFF_B, ws+OFF_C, ws+OFF_DT, ws+OFF_DE,
        ws+OFF_YL, ws+OFF_CA, ws+OFF_U, ws+OFF_AS);
    k4_seg<<<NB, 256, 0, stream>>>(ws+OFF_U, ws+OFF_AS, ws+OFF_HI);
    k5_epi<<<NB*NCHK, 256, 0, stream>>>(x, ws+OFF_GT, ws+OFF_XR, ws+OFF_C,
        ws+OFF_YL, ws+OFF_CA, ws+OFF_HI, ipw, ipb, Dv, norm_w, out_w, out_b,
        detok_w, detok_b, outp);
}

// Round 3
// 166.486 us; speedup vs baseline: 1.0842x; 1.0842x over previous
//
#include <hip/hip_runtime.h>
#include <math.h>

#define NB 16
#define CF 64
#define LL 16384
#define GG 8
#define NH 2
#define NSEG 64
#define SEG 256
#define CHUNK 64

static constexpr size_t OFF_GT = 0;
static constexpr size_t OFF_C  = OFF_GT + (size_t)NB*LL*GG;
static constexpr size_t OFF_YL = OFF_C  + (size_t)NB*LL*16;
static constexpr size_t OFF_CA = OFF_YL + (size_t)NB*LL*16;
static constexpr size_t OFF_U  = OFF_CA + (size_t)NB*LL*NH;
static constexpr size_t OFF_AS = OFF_U  + (size_t)NB*NSEG*256;
static constexpr size_t OFF_HI = OFF_AS + (size_t)NB*NSEG*NH;
static constexpr size_t OFF_G2 = OFF_HI + (size_t)NB*NSEG*256;
static constexpr size_t WS_FLOATS = OFF_G2 + (size_t)NB*LL*GG;

__device__ __forceinline__ float siluf(float v){ return v / (1.f + __expf(-v)); }
__device__ __forceinline__ float softplusf(float v){ return v > 20.f ? v : log1pf(__expf(v)); }

__device__ __forceinline__ void load8(float* d, const float* p){
    float4 a = ((const float4*)p)[0];
    float4 b = ((const float4*)p)[1];
    d[0]=a.x; d[1]=a.y; d[2]=a.z; d[3]=a.w;
    d[4]=b.x; d[5]=b.y; d[6]=b.z; d[7]=b.w;
}
__device__ __forceinline__ void load16(float* d, const float* p){
    load8(d, p); load8(d+8, p+8);
}

// K1a: tokenize x -> gt.  Streaming GEMM, float4 along l, 4 l per thread.
__global__ __launch_bounds__(256) void k1a_tok(
    const float* __restrict__ x, const float* __restrict__ tok_w,
    const float* __restrict__ tok_b, float* __restrict__ gtw)
{
    __shared__ float s_tok[GG*CF];
    int tid = threadIdx.x;
    int b  = blockIdx.x >> 4;
    int ck = blockIdx.x & 15;
    int l0 = (ck << 10) + (tid << 2);
    for (int i = tid; i < GG*CF; i += 256) s_tok[i] = tok_w[i];
    __syncthreads();
    float acc[4][GG];
    #pragma unroll
    for (int r = 0; r < 4; ++r)
        #pragma unroll
        for (int g = 0; g < GG; ++g) acc[r][g] = tok_b[g];
    const float* xb = x + (size_t)b*CF*LL + l0;
    #pragma unroll 8
    for (int c = 0; c < CF; ++c) {
        float4 xv = *(const float4*)(xb + (size_t)c*LL);
        float xa[4] = {xv.x, xv.y, xv.z, xv.w};
        #pragma unroll
        for (int g = 0; g < GG; ++g) {
            float w = s_tok[g*CF + c];
            #pragma unroll
            for (int r = 0; r < 4; ++r) acc[r][g] = fmaf(xa[r], w, acc[r][g]);
        }
    }
    float* gp = gtw + ((size_t)b*LL + l0)*GG;
    #pragma unroll
    for (int r = 0; r < 4; ++r) {
        ((float4*)gp)[r*2+0] = make_float4(acc[r][0],acc[r][1],acc[r][2],acc[r][3]);
        ((float4*)gp)[r*2+1] = make_float4(acc[r][4],acc[r][5],acc[r][6],acc[r][7]);
    }
}

// K1b3: fused in_proj(ch 16..65) + causal conv3 + silu + dt/dec + segmented scan.
__global__ __launch_bounds__(256, 4) void k1b3_conv_scan(
    const float* __restrict__ gtw,
    const float* __restrict__ ipw, const float* __restrict__ ipb,
    const float* __restrict__ cw, const float* __restrict__ cb,
    const float* __restrict__ A_log, const float* __restrict__ dt_bias,
    const float* __restrict__ Dv,
    float* __restrict__ cmw, float* __restrict__ ylw, float* __restrict__ caw,
    float* __restrict__ Uw, float* __restrict__ Asw)
{
    __shared__ float s_v[CHUNK*49];          // post-conv xBC, pad 49 (conflict-free)
    __shared__ float s_y[CHUNK*16];
    __shared__ float s_dt[CHUNK*2], s_de[CHUNK*2], s_ca[CHUNK*2];
    __shared__ float s_ipw[48*GG], s_ipb[48], s_cw[48*3], s_cb[48], s_wdt[2*GG];
    int tid = threadIdx.x;
    int b  = blockIdx.x >> 6;
    int sg = blockIdx.x & 63;
    int t0 = sg << 8;
    for (int i = tid; i < 48*GG; i += 256) s_ipw[i] = ipw[16*GG + i];
    if (tid < 48) { s_ipb[tid] = ipb[16+tid]; s_cb[tid] = cb[tid]; }
    else if (tid >= 64 && tid < 64+144) s_cw[tid-64] = cw[tid-64];
    else if (tid >= 224 && tid < 240) s_wdt[tid-224] = ipw[64*GG + (tid-224)];
    __syncthreads();
    int q = tid >> 6, r = tid & 63;
    int he = tid >> 7, p = (tid >> 4) & 7, n = tid & 15;
    float D_he = Dv[he];
    float a0exp = __expf(A_log[0]), a1exp = __expf(A_log[1]);
    float dtb0 = dt_bias[0], dtb1 = dt_bias[1];
    float bdt0 = ipb[64], bdt1 = ipb[65];
    float h = 0.f, cA = 1.f;
    for (int c0 = 0; c0 < SEG; c0 += CHUNK) {
        int l = t0 + c0 + r;
        size_t grow = ((size_t)b*LL + l)*GG;
        float gv0[8], gv1[8], gv2[8];
        #pragma unroll
        for (int g = 0; g < 8; ++g) { gv1[g] = 0.f; gv2[g] = 0.f; }
        load8(gv0, gtw + grow);
        bool h1 = (l >= 1), h2 = (l >= 2);
        if (h1) load8(gv1, gtw + grow - GG);
        if (h2) load8(gv2, gtw + grow - 2*GG);
        #pragma unroll
        for (int k = 0; k < 12; ++k) {
            int ch = q*12 + k;
            float tA = s_ipb[ch], tB = s_ipb[ch], tC = s_ipb[ch];
            #pragma unroll
            for (int g = 0; g < 8; ++g) {
                float wv = s_ipw[ch*8+g];
                tA = fmaf(gv0[g], wv, tA);
                tB = fmaf(gv1[g], wv, tB);
                tC = fmaf(gv2[g], wv, tC);
            }
            if (!h1) tB = 0.f;
            if (!h2) tC = 0.f;
            float a = s_cb[ch];
            a = fmaf(tC, s_cw[ch*3+0], a);
            a = fmaf(tB, s_cw[ch*3+1], a);
            a = fmaf(tA, s_cw[ch*3+2], a);
            s_v[r*49 + ch] = siluf(a);
        }
        if (q == 0) {                                    // dt / dec for row r
            float d0 = bdt0, d1 = bdt1;
            #pragma unroll
            for (int g = 0; g < 8; ++g) {
                d0 = fmaf(gv0[g], s_wdt[g],   d0);
                d1 = fmaf(gv0[g], s_wdt[8+g], d1);
            }
            float dt0 = softplusf(d0 + dtb0);
            float dt1 = softplusf(d1 + dtb1);
            s_dt[r*2+0] = dt0;              s_dt[r*2+1] = dt1;
            s_de[r*2+0] = __expf(-dt0*a0exp); s_de[r*2+1] = __expf(-dt1*a1exp);
        }
        __syncthreads();
        {   // write C tile out (needed by k5a)
            int rr = tid >> 2, qq = tid & 3;
            const float* sp = &s_v[rr*49 + 32 + qq*4];
            ((float4*)(cmw + ((size_t)b*LL + t0 + c0)*16))[tid] =
                make_float4(sp[0], sp[1], sp[2], sp[3]);
        }
        for (int tt = 0; tt < CHUNK; ++tt) {             // scan
            float a  = s_de[tt*2 + he];
            float xv = s_v[tt*49 + he*8 + p];
            float u  = s_dt[tt*2 + he] * xv * s_v[tt*49 + 16 + n];
            h = fmaf(a, h, u);
            cA *= a;
            float v = h * s_v[tt*49 + 32 + n];
            v += __shfl_xor(v, 1);
            v += __shfl_xor(v, 2);
            v += __shfl_xor(v, 4);
            v += __shfl_xor(v, 8);
            if (n == 0) s_y[tt*16 + he*8 + p] = fmaf(D_he, xv, v);   // D*x folded in
            if ((tid & 127) == 0) s_ca[tt*2 + he] = cA;
        }
        __syncthreads();
        size_t base = (size_t)b*LL + t0 + c0;
        ((float4*)(ylw + base*16))[tid] = ((float4*)s_y)[tid];
        if (tid < 32) ((float4*)(caw + base*2))[tid] = ((float4*)s_ca)[tid];
        __syncthreads();
    }
    Uw[(size_t)blockIdx.x*256 + tid] = h;
    if ((tid & 127) == 0) Asw[blockIdx.x*NH + he] = cA;
}

// K4: inter-segment state scan, prefetched
__global__ void k4_seg(const float* __restrict__ Uw, const float* __restrict__ Asw,
                       float* __restrict__ hiw)
{
    __shared__ float s_as[NSEG*NH];
    int b = blockIdx.x, tid = threadIdx.x, he = tid >> 7;
    for (int i = tid; i < NSEG*NH; i += 256) s_as[i] = Asw[b*NSEG*NH + i];
    __syncthreads();
    size_t base = (size_t)b*NSEG*256;
    float h = 0.f;
    float un = Uw[base + tid];
    for (int s = 0; s < NSEG; ++s) {
        float u = un;
        if (s < NSEG-1) un = Uw[base + (size_t)(s+1)*256 + tid];
        hiw[base + (size_t)s*256 + tid] = h;
        h = fmaf(s_as[s*2 + he], h, u);
    }
}

// K5a: correction + silu(z) gate + RMSNorm + out proj + gt residual -> g2
__global__ __launch_bounds__(256, 4) void k5a_epi(
    const float* __restrict__ gtw, const float* __restrict__ cmw,
    const float* __restrict__ ylw, const float* __restrict__ caw,
    const float* __restrict__ hiw,
    const float* __restrict__ ipw, const float* __restrict__ ipb,
    const float* __restrict__ norm_w,
    const float* __restrict__ out_w, const float* __restrict__ out_b,
    float* __restrict__ g2w)
{
    __shared__ float s_hin[256];
    __shared__ float s_zw[16*GG], s_ow[GG*16];
    int tid = threadIdx.x;
    int b  = blockIdx.x >> 6;
    int ck = blockIdx.x & 63;
    size_t pb = (size_t)b*LL + (ck<<8) + tid;
    s_hin[tid] = hiw[(size_t)blockIdx.x*256 + tid];
    if (tid < 128) s_zw[tid] = ipw[tid];
    else if (tid < 256 && tid-128 < GG*16) s_ow[tid-128] = out_w[tid-128];
    __syncthreads();
    float gv[8]; load8(gv, gtw + pb*GG);
    float Cv[16], ylv[16];
    load16(Cv,  cmw + pb*16);
    load16(ylv, ylw + pb*16);
    float2 ca = *(const float2*)(caw + pb*2);
    float vv[16], ss = 0.f;
    #pragma unroll
    for (int hp = 0; hp < 16; ++hp) {
        float dot = 0.f;
        #pragma unroll
        for (int nn = 0; nn < 16; ++nn)
            dot = fmaf(Cv[nn], s_hin[(hp>>3)*128 + (hp&7)*16 + nn], dot);
        float zz = ipb[hp];
        #pragma unroll
        for (int g = 0; g < GG; ++g) zz = fmaf(gv[g], s_zw[hp*GG+g], zz);
        float y = fmaf((hp>>3) ? ca.y : ca.x, dot, ylv[hp]);
        float w = y * siluf(zz);
        vv[hp] = w; ss = fmaf(w, w, ss);
    }
    float rn = rsqrtf(ss*(1.f/16.f) + 1e-5f);
    float o[8];
    #pragma unroll
    for (int g = 0; g < GG; ++g) o[g] = out_b[g] + gv[g];
    #pragma unroll
    for (int hp = 0; hp < 16; ++hp) {
        float wv = vv[hp] * rn * norm_w[hp];
        #pragma unroll
        for (int g = 0; g < GG; ++g) o[g] = fmaf(wv, s_ow[g*16+hp], o[g]);
    }
    float* gp = g2w + pb*GG;
    ((float4*)gp)[0] = make_float4(o[0],o[1],o[2],o[3]);
    ((float4*)gp)[1] = make_float4(o[4],o[5],o[6],o[7]);
}

// K5b: out = x + detok(g2) + detok_b.  float4 along l, 4 l per thread.
__global__ __launch_bounds__(256, 4) void k5b_detok(
    const float* __restrict__ x, const float* __restrict__ g2w,
    const float* __restrict__ dkw, const float* __restrict__ dkb,
    float* __restrict__ outp)
{
    __shared__ float s_dw[CF*GG];
    __shared__ float s_db[CF];
    int tid = threadIdx.x;
    int b  = blockIdx.x >> 4;
    int ck = blockIdx.x & 15;
    int l0 = (ck << 10) + (tid << 2);
    for (int i = tid; i < CF*GG; i += 256) s_dw[i] = dkw[i];
    if (tid < CF) s_db[tid] = dkb[tid];
    __syncthreads();
    float g2v[4][8];
    const float* gp = g2w + ((size_t)b*LL + l0)*GG;
    #pragma unroll
    for (int r = 0; r < 4; ++r) load8(g2v[r], gp + r*GG);
    const float* xb = x + (size_t)b*CF*LL + l0;
    float* ob = outp + (size_t)b*CF*LL + l0;
    #pragma unroll 4
    for (int c = 0; c < CF; ++c) {
        float4 xv = *(const float4*)(xb + (size_t)c*LL);
        float bias = s_db[c];
        float oa[4] = {xv.x+bias, xv.y+bias, xv.z+bias, xv.w+bias};
        #pragma unroll
        for (int g = 0; g < GG; ++g) {
            float w = s_dw[c*GG+g];
            #pragma unroll
            for (int r = 0; r < 4; ++r) oa[r] = fmaf(g2v[r][g], w, oa[r]);
        }
        *(float4*)(ob + (size_t)c*LL) = make_float4(oa[0],oa[1],oa[2],oa[3]);
    }
}

extern "C" void kernel_launch(void* const* d_in, const int* in_sizes, int n_in,
                              void* d_out, int out_size, void* d_ws, size_t ws_size,
                              hipStream_t stream) {
    const float* x       = (const float*)d_in[0];
    const float* tok_w   = (const float*)d_in[1];
    const float* tok_b   = (const float*)d_in[2];
    const float* detok_w = (const float*)d_in[3];
    const float* detok_b = (const float*)d_in[4];
    const float* ipw     = (const float*)d_in[5];
    const float* ipb     = (const float*)d_in[6];
    const float* cw      = (const float*)d_in[7];
    const float* cb      = (const float*)d_in[8];
    const float* A_log   = (const float*)d_in[9];
    const float* Dv      = (const float*)d_in[10];
    const float* dt_bias = (const float*)d_in[11];
    const float* norm_w  = (const float*)d_in[12];
    const float* out_w   = (const float*)d_in[13];
    const float* out_b   = (const float*)d_in[14];
    float* ws = (float*)d_ws;
    float* outp = (float*)d_out;

    if (ws_size < WS_FLOATS * sizeof(float)) return;

    k1a_tok<<<NB*16, 256, 0, stream>>>(x, tok_w, tok_b, ws+OFF_GT);
    k1b3_conv_scan<<<NB*NSEG, 256, 0, stream>>>(ws+OFF_GT, ipw, ipb, cw, cb,
        A_log, dt_bias, Dv, ws+OFF_C, ws+OFF_YL, ws+OFF_CA, ws+OFF_U, ws+OFF_AS);
    k4_seg<<<NB, 256, 0, stream>>>(ws+OFF_U, ws+OFF_AS, ws+OFF_HI);
    k5a_epi<<<NB*NSEG, 256, 0, stream>>>(ws+OFF_GT, ws+OFF_C, ws+OFF_YL, ws+OFF_CA,
        ws+OFF_HI, ipw, ipb, norm_w, out_w, out_b, ws+OFF_G2);
    k5b_detok<<<NB*16, 256, 0, stream>>>(x, ws+OFF_G2, detok_w, detok_b, outp);
}

// Round 4
// 114.817 us; speedup vs baseline: 1.5721x; 1.4500x over previous
//
#include <hip/hip_runtime.h>
#include <math.h>

#define NB 16
#define CF 64
#define LL 16384
#define GG 8
#define NH 2
#define SEG 64
#define NSEG 256
#define GRP 16
#define NGRP 16
#define CHK 16
#define NCHKS 4

static constexpr size_t OFF_GT = 0;
static constexpr size_t OFF_C  = OFF_GT + (size_t)NB*LL*GG;
static constexpr size_t OFF_YL = OFF_C  + (size_t)NB*LL*16;
static constexpr size_t OFF_CA = OFF_YL + (size_t)NB*LL*16;
static constexpr size_t OFF_PH = OFF_CA + (size_t)NB*LL*NH;
static constexpr size_t OFF_CP = OFF_PH + (size_t)NB*NSEG*256;
static constexpr size_t OFF_U2 = OFF_CP + (size_t)NB*NSEG*NH;
static constexpr size_t OFF_AG = OFF_U2 + (size_t)NB*NGRP*256;
static constexpr size_t OFF_GH = OFF_AG + (size_t)NB*NGRP*NH;
static constexpr size_t OFF_G2 = OFF_GH + (size_t)NB*NGRP*256;
static constexpr size_t WS_FLOATS = OFF_G2 + (size_t)NB*LL*GG;

__device__ __forceinline__ float siluf(float v){ return v / (1.f + __expf(-v)); }
__device__ __forceinline__ float softplusf(float v){ return v > 20.f ? v : log1pf(__expf(v)); }

__device__ __forceinline__ void load8(float* d, const float* p){
    float4 a = ((const float4*)p)[0];
    float4 b = ((const float4*)p)[1];
    d[0]=a.x; d[1]=a.y; d[2]=a.z; d[3]=a.w;
    d[4]=b.x; d[5]=b.y; d[6]=b.z; d[7]=b.w;
}
__device__ __forceinline__ void load16(float* d, const float* p){
    load8(d, p); load8(d+8, p+8);
}

// K1a: tokenize x -> gt.  Streaming GEMM, float4 along l, 4 l per thread.
__global__ __launch_bounds__(256) void k1a_tok(
    const float* __restrict__ x, const float* __restrict__ tok_w,
    const float* __restrict__ tok_b, float* __restrict__ gtw)
{
    __shared__ float s_tok[GG*CF];
    int tid = threadIdx.x;
    int b  = blockIdx.x >> 4;
    int ck = blockIdx.x & 15;
    int l0 = (ck << 10) + (tid << 2);
    for (int i = tid; i < GG*CF; i += 256) s_tok[i] = tok_w[i];
    __syncthreads();
    float acc[4][GG];
    #pragma unroll
    for (int r = 0; r < 4; ++r)
        #pragma unroll
        for (int g = 0; g < GG; ++g) acc[r][g] = tok_b[g];
    const float* xb = x + (size_t)b*CF*LL + l0;
    #pragma unroll 8
    for (int c = 0; c < CF; ++c) {
        float4 xv = *(const float4*)(xb + (size_t)c*LL);
        float xa[4] = {xv.x, xv.y, xv.z, xv.w};
        #pragma unroll
        for (int g = 0; g < GG; ++g) {
            float w = s_tok[g*CF + c];
            #pragma unroll
            for (int r = 0; r < 4; ++r) acc[r][g] = fmaf(xa[r], w, acc[r][g]);
        }
    }
    float* gp = gtw + ((size_t)b*LL + l0)*GG;
    #pragma unroll
    for (int r = 0; r < 4; ++r) {
        ((float4*)gp)[r*2+0] = make_float4(acc[r][0],acc[r][1],acc[r][2],acc[r][3]);
        ((float4*)gp)[r*2+1] = make_float4(acc[r][4],acc[r][5],acc[r][6],acc[r][7]);
    }
}

// K2: fused in_proj + conv3 + silu + dt/dec + register-state scan + intra-group scan.
// Block = (b, group of 16 segments of 64 steps). Thread staging role: (sj=tid>>4, tl=tid&15).
// Thread scan role: (sj, he=(tid>>3)&1, p=tid&7) holding h[16] in registers.
__global__ __launch_bounds__(256, 1) void k2_fused(
    const float* __restrict__ gtw,
    const float* __restrict__ ipw, const float* __restrict__ ipb,
    const float* __restrict__ cw, const float* __restrict__ cb,
    const float* __restrict__ A_log, const float* __restrict__ dt_bias,
    const float* __restrict__ Dv,
    float* __restrict__ cmw, float* __restrict__ ylw, float* __restrict__ caw,
    float* __restrict__ phw, float* __restrict__ cpw,
    float* __restrict__ U2w, float* __restrict__ Agw)
{
    __shared__ float s_x [16][17][20];     // xr tile; y written in-place after x consumed
    __shared__ float s_B [16][17][20];
    __shared__ float s_Ct[16][17][20];
    __shared__ float s_dt[16][17][2], s_de[16][17][2], s_ca[16][17][2];
    __shared__ float s_U[16][2][8][17];
    __shared__ float s_cAs[16][2];
    __shared__ float s_ipw[48*8];
    __shared__ float s_ipb2[48], s_cw2[144], s_cb2[48], s_wdt[16];

    int tid = threadIdx.x;
    int b = blockIdx.x >> 4, grp = blockIdx.x & 15;
    for (int i = tid; i < 384; i += 256) s_ipw[i] = ipw[128 + i];
    if (tid < 48) { s_ipb2[tid] = ipb[16 + tid]; s_cb2[tid] = cb[tid]; }
    else if (tid >= 64 && tid < 208) s_cw2[tid - 64] = cw[tid - 64];
    else if (tid >= 224 && tid < 240) s_wdt[tid - 224] = ipw[512 + (tid - 224)];
    __syncthreads();

    int sj = tid >> 4, tl = tid & 15;
    int he = (tid >> 3) & 1, p = tid & 7;
    int hp = he * 8 + p;
    int eb = he * 128 + p * 16;
    float a0e = __expf(A_log[0]), a1e = __expf(A_log[1]);
    float dtb0 = dt_bias[0], dtb1 = dt_bias[1];
    float bdt0 = ipb[64], bdt1 = ipb[65];
    float D_he = Dv[he];
    float h[16];
    #pragma unroll
    for (int n = 0; n < 16; ++n) h[n] = 0.f;
    float cA = 1.f;
    int lb = grp * 1024 + sj * 64;

    for (int c = 0; c < NCHKS; ++c) {
        int l = lb + c * CHK + tl;
        size_t gb = ((size_t)b * LL + l) * GG;
        float g0[8], g1[8], g2v[8];
        #pragma unroll
        for (int g = 0; g < 8; ++g) { g1[g] = 0.f; g2v[g] = 0.f; }
        load8(g0, gtw + gb);
        if (l >= 1) load8(g1, gtw + gb - GG);
        if (l >= 2) load8(g2v, gtw + gb - 2*GG);
        float vals[48];
        #pragma unroll
        for (int ch = 0; ch < 48; ++ch) {
            float4 w0 = *(const float4*)&s_ipw[ch*8];
            float4 w1 = *(const float4*)&s_ipw[ch*8+4];
            float wv[8] = {w0.x,w0.y,w0.z,w0.w,w1.x,w1.y,w1.z,w1.w};
            float bia = s_ipb2[ch];
            float tA = bia, tB = bia, tC = bia;
            #pragma unroll
            for (int g = 0; g < 8; ++g) {
                tA = fmaf(g0[g],  wv[g], tA);
                tB = fmaf(g1[g],  wv[g], tB);
                tC = fmaf(g2v[g], wv[g], tC);
            }
            if (l < 1) tB = 0.f;
            if (l < 2) tC = 0.f;
            float a = s_cb2[ch];
            a = fmaf(tC, s_cw2[ch*3+0], a);
            a = fmaf(tB, s_cw2[ch*3+1], a);
            a = fmaf(tA, s_cw2[ch*3+2], a);
            vals[ch] = siluf(a);
        }
        #pragma unroll
        for (int q = 0; q < 4; ++q) {
            int ph_ = ((q + tl) & 3) * 4;
            *(float4*)&s_x [sj][tl][ph_] = make_float4(vals[q*4+0],vals[q*4+1],vals[q*4+2],vals[q*4+3]);
            *(float4*)&s_B [sj][tl][ph_] = make_float4(vals[16+q*4+0],vals[16+q*4+1],vals[16+q*4+2],vals[16+q*4+3]);
            *(float4*)&s_Ct[sj][tl][ph_] = make_float4(vals[32+q*4+0],vals[32+q*4+1],vals[32+q*4+2],vals[32+q*4+3]);
        }
        {   // C straight to global (coalesced per-row float4s)
            size_t pb = (size_t)b * LL + l;
            float4* cp4 = (float4*)(cmw + pb*16);
            #pragma unroll
            for (int q = 0; q < 4; ++q)
                cp4[q] = make_float4(vals[32+q*4+0],vals[32+q*4+1],vals[32+q*4+2],vals[32+q*4+3]);
        }
        {
            float d0 = bdt0, d1 = bdt1;
            #pragma unroll
            for (int g = 0; g < 8; ++g) {
                d0 = fmaf(g0[g], s_wdt[g],   d0);
                d1 = fmaf(g0[g], s_wdt[8+g], d1);
            }
            float dt0 = softplusf(d0 + dtb0), dt1 = softplusf(d1 + dtb1);
            *(float2*)&s_dt[sj][tl][0] = make_float2(dt0, dt1);
            *(float2*)&s_de[sj][tl][0] = make_float2(__expf(-dt0*a0e), __expf(-dt1*a1e));
        }
        __syncthreads();
        for (int t = 0; t < CHK; ++t) {
            float a   = s_de[sj][t][he];
            float dtv = s_dt[sj][t][he];
            float xv  = s_x[sj][t][(((hp>>2)+t)&3)*4 + (hp&3)];
            float u = dtv * xv;
            float Bv[16], Cv[16];
            #pragma unroll
            for (int q = 0; q < 4; ++q) {
                float4 bq = *(const float4*)&s_B [sj][t][((q+t)&3)*4];
                float4 cq = *(const float4*)&s_Ct[sj][t][((q+t)&3)*4];
                Bv[q*4+0]=bq.x; Bv[q*4+1]=bq.y; Bv[q*4+2]=bq.z; Bv[q*4+3]=bq.w;
                Cv[q*4+0]=cq.x; Cv[q*4+1]=cq.y; Cv[q*4+2]=cq.z; Cv[q*4+3]=cq.w;
            }
            float y = 0.f;
            #pragma unroll
            for (int n = 0; n < 16; ++n) {
                h[n] = fmaf(a, h[n], u * Bv[n]);
                y = fmaf(h[n], Cv[n], y);
            }
            cA *= a;
            // y overwrites x slot (x already consumed by its owner lane this step)
            s_x[sj][t][(((hp>>2)+t)&3)*4 + (hp&3)] = fmaf(D_he, xv, y);
            if (p == 0) s_ca[sj][t][he] = cA;
        }
        __syncthreads();
        {   // bulk store y, ca
            size_t pb = (size_t)b * LL + l;
            float4* yp4 = (float4*)(ylw + pb*16);
            #pragma unroll
            for (int q = 0; q < 4; ++q)
                yp4[q] = *(const float4*)&s_x[sj][tl][((q+tl)&3)*4];
            *(float2*)(caw + pb*2) = *(const float2*)&s_ca[sj][tl][0];
        }
        __syncthreads();
    }

    // ---- intra-group (16 seg) inclusive scan done per-lane from LDS ----
    #pragma unroll
    for (int n = 0; n < 16; ++n) s_U[sj][he][p][n] = h[n];
    if (p == 0) s_cAs[sj][he] = cA;
    __syncthreads();
    float hin[16];
    #pragma unroll
    for (int n = 0; n < 16; ++n) hin[n] = 0.f;
    float cp = 1.f;
    for (int j = 0; j < GRP-1; ++j) {
        if (j < sj) {
            float Aj = s_cAs[j][he];
            #pragma unroll
            for (int n = 0; n < 16; ++n) hin[n] = fmaf(Aj, hin[n], s_U[j][he][p][n]);
            cp *= Aj;
        }
    }
    int seg = grp * GRP + sj;
    {
        float* php = phw + (((size_t)b*NSEG + seg) << 8) + eb;
        #pragma unroll
        for (int q = 0; q < 4; ++q)
            ((float4*)php)[q] = make_float4(hin[q*4+0],hin[q*4+1],hin[q*4+2],hin[q*4+3]);
        if (p == 0) cpw[((size_t)b*NSEG + seg)*2 + he] = cp;
    }
    if (sj == GRP-1) {
        float A15 = s_cAs[15][he];
        float* u2p = U2w + (((size_t)b*NGRP + grp) << 8) + eb;
        #pragma unroll
        for (int q = 0; q < 4; ++q) {
            float4 v4;
            v4.x = fmaf(A15, hin[q*4+0], h[q*4+0]);
            v4.y = fmaf(A15, hin[q*4+1], h[q*4+1]);
            v4.z = fmaf(A15, hin[q*4+2], h[q*4+2]);
            v4.w = fmaf(A15, hin[q*4+3], h[q*4+3]);
            ((float4*)u2p)[q] = v4;
        }
        if (p == 0) Agw[((size_t)b*NGRP + grp)*2 + he] = cp * A15;
    }
}

// K4b: scan 16 group summaries (fully prefetched, 16 steps).
__global__ void k4b_grp(const float* __restrict__ U2w, const float* __restrict__ Agw,
                        float* __restrict__ ghw)
{
    int b = blockIdx.x, e = threadIdx.x, he = e >> 7;
    float u[NGRP], ag[NGRP];
    #pragma unroll
    for (int g = 0; g < NGRP; ++g) {
        u[g]  = U2w[(((size_t)b*NGRP + g) << 8) + e];
        ag[g] = Agw[((size_t)b*NGRP + g)*2 + he];
    }
    float h = 0.f;
    #pragma unroll
    for (int g = 0; g < NGRP; ++g) {
        ghw[(((size_t)b*NGRP + g) << 8) + e] = h;
        h = fmaf(ag[g], h, u[g]);
    }
}

// K5a: hin reconstruction + correction + silu(z) gate + RMSNorm + out proj + gt residual -> g2
__global__ __launch_bounds__(256, 4) void k5a_epi(
    const float* __restrict__ gtw, const float* __restrict__ cmw,
    const float* __restrict__ ylw, const float* __restrict__ caw,
    const float* __restrict__ phw, const float* __restrict__ cpw,
    const float* __restrict__ ghw,
    const float* __restrict__ ipw, const float* __restrict__ ipb,
    const float* __restrict__ norm_w,
    const float* __restrict__ out_w, const float* __restrict__ out_b,
    float* __restrict__ g2w)
{
    __shared__ float s_hin[4][256];
    __shared__ float s_zw[16*GG], s_ow[GG*16];
    int tid = threadIdx.x;
    int b  = blockIdx.x >> 6;
    int ck = blockIdx.x & 63;           // 256-row chunk = 4 segs
    int grp = ck >> 2;
    float gh = ghw[(((size_t)b*NGRP + grp) << 8) + tid];
    #pragma unroll
    for (int k = 0; k < 4; ++k) {
        int seg = ck*4 + k;
        float cpv = cpw[((size_t)b*NSEG + seg)*2 + (tid >> 7)];
        s_hin[k][tid] = fmaf(cpv, gh, phw[(((size_t)b*NSEG + seg) << 8) + tid]);
    }
    if (tid < 128) s_zw[tid] = ipw[tid];
    else s_ow[tid-128] = out_w[tid-128];
    __syncthreads();
    size_t pb = (size_t)b*LL + (ck<<8) + tid;
    int sub = tid >> 6;
    float gv[8]; load8(gv, gtw + pb*GG);
    float Cv[16], ylv[16];
    load16(Cv,  cmw + pb*16);
    load16(ylv, ylw + pb*16);
    float2 ca = *(const float2*)(caw + pb*2);
    float vv[16], ss = 0.f;
    #pragma unroll
    for (int hp = 0; hp < 16; ++hp) {
        float dot = 0.f;
        #pragma unroll
        for (int nn = 0; nn < 16; ++nn)
            dot = fmaf(Cv[nn], s_hin[sub][(hp>>3)*128 + (hp&7)*16 + nn], dot);
        float zz = ipb[hp];
        #pragma unroll
        for (int g = 0; g < GG; ++g) zz = fmaf(gv[g], s_zw[hp*GG+g], zz);
        float y = fmaf((hp>>3) ? ca.y : ca.x, dot, ylv[hp]);
        float w = y * siluf(zz);
        vv[hp] = w; ss = fmaf(w, w, ss);
    }
    float rn = rsqrtf(ss*(1.f/16.f) + 1e-5f);
    float o[8];
    #pragma unroll
    for (int g = 0; g < GG; ++g) o[g] = out_b[g] + gv[g];
    #pragma unroll
    for (int hp = 0; hp < 16; ++hp) {
        float wv = vv[hp] * rn * norm_w[hp];
        #pragma unroll
        for (int g = 0; g < GG; ++g) o[g] = fmaf(wv, s_ow[g*16+hp], o[g]);
    }
    float* gp = g2w + pb*GG;
    ((float4*)gp)[0] = make_float4(o[0],o[1],o[2],o[3]);
    ((float4*)gp)[1] = make_float4(o[4],o[5],o[6],o[7]);
}

// K5b: out = x + detok(g2) + detok_b.  float4 along l, 4 l per thread.
__global__ __launch_bounds__(256, 4) void k5b_detok(
    const float* __restrict__ x, const float* __restrict__ g2w,
    const float* __restrict__ dkw, const float* __restrict__ dkb,
    float* __restrict__ outp)
{
    __shared__ float s_dw[CF*GG];
    __shared__ float s_db[CF];
    int tid = threadIdx.x;
    int b  = blockIdx.x >> 4;
    int ck = blockIdx.x & 15;
    int l0 = (ck << 10) + (tid << 2);
    for (int i = tid; i < CF*GG; i += 256) s_dw[i] = dkw[i];
    if (tid < CF) s_db[tid] = dkb[tid];
    __syncthreads();
    float g2v[4][8];
    const float* gp = g2w + ((size_t)b*LL + l0)*GG;
    #pragma unroll
    for (int r = 0; r < 4; ++r) load8(g2v[r], gp + r*GG);
    const float* xb = x + (size_t)b*CF*LL + l0;
    float* ob = outp + (size_t)b*CF*LL + l0;
    #pragma unroll 4
    for (int c = 0; c < CF; ++c) {
        float4 xv = *(const float4*)(xb + (size_t)c*LL);
        float bias = s_db[c];
        float oa[4] = {xv.x+bias, xv.y+bias, xv.z+bias, xv.w+bias};
        #pragma unroll
        for (int g = 0; g < GG; ++g) {
            float w = s_dw[c*GG+g];
            #pragma unroll
            for (int r = 0; r < 4; ++r) oa[r] = fmaf(g2v[r][g], w, oa[r]);
        }
        *(float4*)(ob + (size_t)c*LL) = make_float4(oa[0],oa[1],oa[2],oa[3]);
    }
}

extern "C" void kernel_launch(void* const* d_in, const int* in_sizes, int n_in,
                              void* d_out, int out_size, void* d_ws, size_t ws_size,
                              hipStream_t stream) {
    const float* x       = (const float*)d_in[0];
    const float* tok_w   = (const float*)d_in[1];
    const float* tok_b   = (const float*)d_in[2];
    const float* detok_w = (const float*)d_in[3];
    const float* detok_b = (const float*)d_in[4];
    const float* ipw     = (const float*)d_in[5];
    const float* ipb     = (const float*)d_in[6];
    const float* cw      = (const float*)d_in[7];
    const float* cb      = (const float*)d_in[8];
    const float* A_log   = (const float*)d_in[9];
    const float* Dv      = (const float*)d_in[10];
    const float* dt_bias = (const float*)d_in[11];
    const float* norm_w  = (const float*)d_in[12];
    const float* out_w   = (const float*)d_in[13];
    const float* out_b   = (const float*)d_in[14];
    float* ws = (float*)d_ws;
    float* outp = (float*)d_out;

    if (ws_size < WS_FLOATS * sizeof(float)) return;

    k1a_tok<<<NB*16, 256, 0, stream>>>(x, tok_w, tok_b, ws+OFF_GT);
    k2_fused<<<NB*NGRP, 256, 0, stream>>>(ws+OFF_GT, ipw, ipb, cw, cb,
        A_log, dt_bias, Dv, ws+OFF_C, ws+OFF_YL, ws+OFF_CA,
        ws+OFF_PH, ws+OFF_CP, ws+OFF_U2, ws+OFF_AG);
    k4b_grp<<<NB, 256, 0, stream>>>(ws+OFF_U2, ws+OFF_AG, ws+OFF_GH);
    k5a_epi<<<NB*64, 256, 0, stream>>>(ws+OFF_GT, ws+OFF_C, ws+OFF_YL, ws+OFF_CA,
        ws+OFF_PH, ws+OFF_CP, ws+OFF_GH, ipw, ipb, norm_w, out_w, out_b, ws+OFF_G2);
    k5b_detok<<<NB*16, 256, 0, stream>>>(x, ws+OFF_G2, detok_w, detok_b, outp);
}

// Round 5
// 110.099 us; speedup vs baseline: 1.6395x; 1.0429x over previous
//
#include <hip/hip_runtime.h>
#include <math.h>

#define NB 16
#define CF 64
#define LL 16384
#define GG 8
#define NH 2
#define SEG 32
#define NSEG 512
#define GRP 16
#define NGRP 32
#define CHK 16
#define NCHKS 2

static constexpr size_t OFF_GT = 0;
static constexpr size_t OFF_C  = OFF_GT + (size_t)NB*LL*GG;
static constexpr size_t OFF_YL = OFF_C  + (size_t)NB*LL*16;
static constexpr size_t OFF_CA = OFF_YL + (size_t)NB*LL*16;
static constexpr size_t OFF_PH = OFF_CA + (size_t)NB*LL*NH;
static constexpr size_t OFF_CP = OFF_PH + (size_t)NB*NSEG*256;
static constexpr size_t OFF_U2 = OFF_CP + (size_t)NB*NSEG*NH;
static constexpr size_t OFF_AG = OFF_U2 + (size_t)NB*NGRP*256;
static constexpr size_t OFF_GH = OFF_AG + (size_t)NB*NGRP*NH;
static constexpr size_t OFF_G2 = OFF_GH + (size_t)NB*NGRP*256;
static constexpr size_t WS_FLOATS = OFF_G2 + (size_t)NB*LL*GG;

__device__ __forceinline__ float siluf(float v){ return v / (1.f + __expf(-v)); }
__device__ __forceinline__ float softplusf(float v){ return v > 20.f ? v : log1pf(__expf(v)); }

__device__ __forceinline__ void load8(float* d, const float* p){
    float4 a = ((const float4*)p)[0];
    float4 b = ((const float4*)p)[1];
    d[0]=a.x; d[1]=a.y; d[2]=a.z; d[3]=a.w;
    d[4]=b.x; d[5]=b.y; d[6]=b.z; d[7]=b.w;
}
__device__ __forceinline__ void load16(float* d, const float* p){
    load8(d, p); load8(d+8, p+8);
}

// K1a: tokenize x -> gt.
__global__ __launch_bounds__(256) void k1a_tok(
    const float* __restrict__ x, const float* __restrict__ tok_w,
    const float* __restrict__ tok_b, float* __restrict__ gtw)
{
    __shared__ float s_tok[GG*CF];
    int tid = threadIdx.x;
    int b  = blockIdx.x >> 4;
    int ck = blockIdx.x & 15;
    int l0 = (ck << 10) + (tid << 2);
    for (int i = tid; i < GG*CF; i += 256) s_tok[i] = tok_w[i];
    __syncthreads();
    float acc[4][GG];
    #pragma unroll
    for (int r = 0; r < 4; ++r)
        #pragma unroll
        for (int g = 0; g < GG; ++g) acc[r][g] = tok_b[g];
    const float* xb = x + (size_t)b*CF*LL + l0;
    #pragma unroll 8
    for (int c = 0; c < CF; ++c) {
        float4 xv = *(const float4*)(xb + (size_t)c*LL);
        float xa[4] = {xv.x, xv.y, xv.z, xv.w};
        #pragma unroll
        for (int g = 0; g < GG; ++g) {
            float w = s_tok[g*CF + c];
            #pragma unroll
            for (int r = 0; r < 4; ++r) acc[r][g] = fmaf(xa[r], w, acc[r][g]);
        }
    }
    float* gp = gtw + ((size_t)b*LL + l0)*GG;
    #pragma unroll
    for (int r = 0; r < 4; ++r) {
        ((float4*)gp)[r*2+0] = make_float4(acc[r][0],acc[r][1],acc[r][2],acc[r][3]);
        ((float4*)gp)[r*2+1] = make_float4(acc[r][4],acc[r][5],acc[r][6],acc[r][7]);
    }
}

// K2: fused in_proj + conv3 + silu + dt/dec + register-state scan + intra-group scan.
// Block = (b, group of 16 segments of 32 steps), 512 blocks, 2 blocks/CU.
__global__ __launch_bounds__(256, 2) void k2_fused(
    const float* __restrict__ gtw,
    const float* __restrict__ ipw, const float* __restrict__ ipb,
    const float* __restrict__ cw, const float* __restrict__ cb,
    const float* __restrict__ A_log, const float* __restrict__ dt_bias,
    const float* __restrict__ Dv,
    float* __restrict__ cmw, float* __restrict__ ylw, float* __restrict__ caw,
    float* __restrict__ phw, float* __restrict__ cpw,
    float* __restrict__ U2w, float* __restrict__ Agw)
{
    __shared__ float s_x [16][17][20];     // xr tile; y written in-place; s_U overlaid at tail
    __shared__ float s_B [16][17][20];
    __shared__ float s_Ct[16][17][20];
    __shared__ float s_dt[16][16][2], s_de[16][16][2], s_ca[16][16][2];
    __shared__ float s_cAs[16][2];
    __shared__ float s_ipw[48*8];
    __shared__ float s_ipb2[48], s_cw2[144], s_cb2[48], s_wdt[16];

    int tid = threadIdx.x;
    int b = blockIdx.x >> 5, grp = blockIdx.x & 31;
    for (int i = tid; i < 384; i += 256) s_ipw[i] = ipw[128 + i];
    if (tid < 48) { s_ipb2[tid] = ipb[16 + tid]; s_cb2[tid] = cb[tid]; }
    else if (tid >= 64 && tid < 208) s_cw2[tid - 64] = cw[tid - 64];
    else if (tid >= 224 && tid < 240) s_wdt[tid - 224] = ipw[512 + (tid - 224)];
    __syncthreads();

    int sj = tid >> 4, tl = tid & 15;
    int he = (tid >> 3) & 1, p = tid & 7;
    int hp = he * 8 + p;
    int eb = he * 128 + p * 16;
    float a0e = __expf(A_log[0]), a1e = __expf(A_log[1]);
    float dtb0 = dt_bias[0], dtb1 = dt_bias[1];
    float bdt0 = ipb[64], bdt1 = ipb[65];
    float D_he = Dv[he];
    float h[16];
    #pragma unroll
    for (int n = 0; n < 16; ++n) h[n] = 0.f;
    float cA = 1.f;
    int lb = grp * (GRP*SEG) + sj * SEG;

    // prefetch chunk 0 gt rows
    float g0[8], g1[8], g2v[8];
    {
        int l = lb + tl;
        size_t gb = ((size_t)b * LL + l) * GG;
        #pragma unroll
        for (int g = 0; g < 8; ++g) { g1[g] = 0.f; g2v[g] = 0.f; }
        load8(g0, gtw + gb);
        if (l >= 1) load8(g1, gtw + gb - GG);
        if (l >= 2) load8(g2v, gtw + gb - 2*GG);
    }

    for (int c = 0; c < NCHKS; ++c) {
        int l = lb + c * CHK + tl;
        float vals[48];
        #pragma unroll
        for (int ch = 0; ch < 48; ++ch) {
            float4 w0 = *(const float4*)&s_ipw[ch*8];
            float4 w1 = *(const float4*)&s_ipw[ch*8+4];
            float wv[8] = {w0.x,w0.y,w0.z,w0.w,w1.x,w1.y,w1.z,w1.w};
            float bia = s_ipb2[ch];
            float tA = bia, tB = bia, tC = bia;
            #pragma unroll
            for (int g = 0; g < 8; ++g) {
                tA = fmaf(g0[g],  wv[g], tA);
                tB = fmaf(g1[g],  wv[g], tB);
                tC = fmaf(g2v[g], wv[g], tC);
            }
            if (l < 1) tB = 0.f;
            if (l < 2) tC = 0.f;
            float a = s_cb2[ch];
            a = fmaf(tC, s_cw2[ch*3+0], a);
            a = fmaf(tB, s_cw2[ch*3+1], a);
            a = fmaf(tA, s_cw2[ch*3+2], a);
            vals[ch] = siluf(a);
        }
        #pragma unroll
        for (int q = 0; q < 4; ++q) {
            int ph_ = ((q + tl) & 3) * 4;
            *(float4*)&s_x [sj][tl][ph_] = make_float4(vals[q*4+0],vals[q*4+1],vals[q*4+2],vals[q*4+3]);
            *(float4*)&s_B [sj][tl][ph_] = make_float4(vals[16+q*4+0],vals[16+q*4+1],vals[16+q*4+2],vals[16+q*4+3]);
            *(float4*)&s_Ct[sj][tl][ph_] = make_float4(vals[32+q*4+0],vals[32+q*4+1],vals[32+q*4+2],vals[32+q*4+3]);
        }
        {   // C straight to global
            size_t pb = (size_t)b * LL + l;
            float4* cp4 = (float4*)(cmw + pb*16);
            #pragma unroll
            for (int q = 0; q < 4; ++q)
                cp4[q] = make_float4(vals[32+q*4+0],vals[32+q*4+1],vals[32+q*4+2],vals[32+q*4+3]);
        }
        {
            float d0 = bdt0, d1 = bdt1;
            #pragma unroll
            for (int g = 0; g < 8; ++g) {
                d0 = fmaf(g0[g], s_wdt[g],   d0);
                d1 = fmaf(g0[g], s_wdt[8+g], d1);
            }
            float dt0 = softplusf(d0 + dtb0), dt1 = softplusf(d1 + dtb1);
            *(float2*)&s_dt[sj][tl][0] = make_float2(dt0, dt1);
            *(float2*)&s_de[sj][tl][0] = make_float2(__expf(-dt0*a0e), __expf(-dt1*a1e));
        }
        // prefetch next chunk gt rows (hide L2 latency under scan)
        if (c + 1 < NCHKS) {
            int l2 = lb + (c+1) * CHK + tl;
            size_t gb2 = ((size_t)b * LL + l2) * GG;
            load8(g0,  gtw + gb2);
            load8(g1,  gtw + gb2 - GG);
            load8(g2v, gtw + gb2 - 2*GG);
        }
        __syncthreads();
        {   // scan with register double-buffer (prefetch t+1 before t's FMA chain)
            float a_c  = s_de[sj][0][he];
            float dt_c = s_dt[sj][0][he];
            float x_c  = s_x[sj][0][(((hp>>2))&3)*4 + (hp&3)];
            float4 bq[4], cq[4];
            #pragma unroll
            for (int q = 0; q < 4; ++q) {
                bq[q] = *(const float4*)&s_B [sj][0][(q&3)*4];
                cq[q] = *(const float4*)&s_Ct[sj][0][(q&3)*4];
            }
            #pragma unroll
            for (int t = 0; t < CHK; ++t) {
                float a = a_c, dtv = dt_c, xv = x_c;
                float4 nb[4], nc[4];
                float na = 0.f, ndt = 0.f, nx = 0.f;
                if (t + 1 < CHK) {
                    na  = s_de[sj][t+1][he];
                    ndt = s_dt[sj][t+1][he];
                    nx  = s_x[sj][t+1][(((hp>>2)+t+1)&3)*4 + (hp&3)];
                    #pragma unroll
                    for (int q = 0; q < 4; ++q) {
                        nb[q] = *(const float4*)&s_B [sj][t+1][((q+t+1)&3)*4];
                        nc[q] = *(const float4*)&s_Ct[sj][t+1][((q+t+1)&3)*4];
                    }
                }
                float u = dtv * xv;
                float Bv[16], Cv[16];
                #pragma unroll
                for (int q = 0; q < 4; ++q) {
                    Bv[q*4+0]=bq[q].x; Bv[q*4+1]=bq[q].y; Bv[q*4+2]=bq[q].z; Bv[q*4+3]=bq[q].w;
                    Cv[q*4+0]=cq[q].x; Cv[q*4+1]=cq[q].y; Cv[q*4+2]=cq[q].z; Cv[q*4+3]=cq[q].w;
                }
                float y = 0.f;
                #pragma unroll
                for (int n = 0; n < 16; ++n) {
                    h[n] = fmaf(a, h[n], u * Bv[n]);
                    y = fmaf(h[n], Cv[n], y);
                }
                cA *= a;
                s_x[sj][t][(((hp>>2)+t)&3)*4 + (hp&3)] = fmaf(D_he, xv, y);
                if (p == 0) s_ca[sj][t][he] = cA;
                a_c = na; dt_c = ndt; x_c = nx;
                #pragma unroll
                for (int q = 0; q < 4; ++q) { bq[q] = nb[q]; cq[q] = nc[q]; }
            }
        }
        __syncthreads();
        {   // bulk store y, ca
            size_t pb = (size_t)b * LL + l;
            float4* yp4 = (float4*)(ylw + pb*16);
            #pragma unroll
            for (int q = 0; q < 4; ++q)
                yp4[q] = *(const float4*)&s_x[sj][tl][((q+tl)&3)*4];
            *(float2*)(caw + pb*2) = *(const float2*)&s_ca[sj][tl][0];
        }
        __syncthreads();
    }

    // ---- intra-group (16 seg) scan; s_U overlaid on s_x (safe after last barrier) ----
    float (*s_U)[2][8][17] = reinterpret_cast<float(*)[2][8][17]>(&s_x[0][0][0]);
    #pragma unroll
    for (int n = 0; n < 16; ++n) s_U[sj][he][p][n] = h[n];
    if (p == 0) s_cAs[sj][he] = cA;
    __syncthreads();
    float hin[16];
    #pragma unroll
    for (int n = 0; n < 16; ++n) hin[n] = 0.f;
    float cp = 1.f;
    for (int j = 0; j < GRP-1; ++j) {
        if (j < sj) {
            float Aj = s_cAs[j][he];
            #pragma unroll
            for (int n = 0; n < 16; ++n) hin[n] = fmaf(Aj, hin[n], s_U[j][he][p][n]);
            cp *= Aj;
        }
    }
    int seg = grp * GRP + sj;
    {
        float* php = phw + (((size_t)b*NSEG + seg) << 8) + eb;
        #pragma unroll
        for (int q = 0; q < 4; ++q)
            ((float4*)php)[q] = make_float4(hin[q*4+0],hin[q*4+1],hin[q*4+2],hin[q*4+3]);
        if (p == 0) cpw[((size_t)b*NSEG + seg)*2 + he] = cp;
    }
    if (sj == GRP-1) {
        float A15 = s_cAs[15][he];
        float* u2p = U2w + (((size_t)b*NGRP + grp) << 8) + eb;
        #pragma unroll
        for (int q = 0; q < 4; ++q) {
            float4 v4;
            v4.x = fmaf(A15, hin[q*4+0], h[q*4+0]);
            v4.y = fmaf(A15, hin[q*4+1], h[q*4+1]);
            v4.z = fmaf(A15, hin[q*4+2], h[q*4+2]);
            v4.w = fmaf(A15, hin[q*4+3], h[q*4+3]);
            ((float4*)u2p)[q] = v4;
        }
        if (p == 0) Agw[((size_t)b*NGRP + grp)*2 + he] = cp * A15;
    }
}

// K4b: scan 32 group summaries (fully prefetched).
__global__ void k4b_grp(const float* __restrict__ U2w, const float* __restrict__ Agw,
                        float* __restrict__ ghw)
{
    int b = blockIdx.x, e = threadIdx.x, he = e >> 7;
    float u[NGRP], ag[NGRP];
    #pragma unroll
    for (int g = 0; g < NGRP; ++g) {
        u[g]  = U2w[(((size_t)b*NGRP + g) << 8) + e];
        ag[g] = Agw[((size_t)b*NGRP + g)*2 + he];
    }
    float h = 0.f;
    #pragma unroll
    for (int g = 0; g < NGRP; ++g) {
        ghw[(((size_t)b*NGRP + g) << 8) + e] = h;
        h = fmaf(ag[g], h, u[g]);
    }
}

// K5a: hin reconstruction + correction + silu(z) gate + RMSNorm + out proj + gt residual -> g2
__global__ __launch_bounds__(256, 4) void k5a_epi(
    const float* __restrict__ gtw, const float* __restrict__ cmw,
    const float* __restrict__ ylw, const float* __restrict__ caw,
    const float* __restrict__ phw, const float* __restrict__ cpw,
    const float* __restrict__ ghw,
    const float* __restrict__ ipw, const float* __restrict__ ipb,
    const float* __restrict__ norm_w,
    const float* __restrict__ out_w, const float* __restrict__ out_b,
    float* __restrict__ g2w)
{
    __shared__ float s_hin[8][256];
    __shared__ float s_zw[16*GG], s_ow[GG*16];
    int tid = threadIdx.x;
    int b  = blockIdx.x >> 6;
    int ck = blockIdx.x & 63;           // 256-row chunk = 8 segs of 32
    int grp = ck >> 1;
    float gh = ghw[(((size_t)b*NGRP + grp) << 8) + tid];
    #pragma unroll
    for (int k = 0; k < 8; ++k) {
        int seg = ck*8 + k;
        float cpv = cpw[((size_t)b*NSEG + seg)*2 + (tid >> 7)];
        s_hin[k][tid] = fmaf(cpv, gh, phw[(((size_t)b*NSEG + seg) << 8) + tid]);
    }
    if (tid < 128) s_zw[tid] = ipw[tid];
    else s_ow[tid-128] = out_w[tid-128];
    __syncthreads();
    size_t pb = (size_t)b*LL + (ck<<8) + tid;
    int sub = tid >> 5;
    float gv[8]; load8(gv, gtw + pb*GG);
    float Cv[16], ylv[16];
    load16(Cv,  cmw + pb*16);
    load16(ylv, ylw + pb*16);
    float2 ca = *(const float2*)(caw + pb*2);
    float vv[16], ss = 0.f;
    #pragma unroll
    for (int hp = 0; hp < 16; ++hp) {
        float dot = 0.f;
        #pragma unroll
        for (int nn = 0; nn < 16; ++nn)
            dot = fmaf(Cv[nn], s_hin[sub][(hp>>3)*128 + (hp&7)*16 + nn], dot);
        float zz = ipb[hp];
        #pragma unroll
        for (int g = 0; g < GG; ++g) zz = fmaf(gv[g], s_zw[hp*GG+g], zz);
        float y = fmaf((hp>>3) ? ca.y : ca.x, dot, ylv[hp]);
        float w = y * siluf(zz);
        vv[hp] = w; ss = fmaf(w, w, ss);
    }
    float rn = rsqrtf(ss*(1.f/16.f) + 1e-5f);
    float o[8];
    #pragma unroll
    for (int g = 0; g < GG; ++g) o[g] = out_b[g] + gv[g];
    #pragma unroll
    for (int hp = 0; hp < 16; ++hp) {
        float wv = vv[hp] * rn * norm_w[hp];
        #pragma unroll
        for (int g = 0; g < GG; ++g) o[g] = fmaf(wv, s_ow[g*16+hp], o[g]);
    }
    float* gp = g2w + pb*GG;
    ((float4*)gp)[0] = make_float4(o[0],o[1],o[2],o[3]);
    ((float4*)gp)[1] = make_float4(o[4],o[5],o[6],o[7]);
}

// K5b: out = x + detok(g2) + detok_b.
__global__ __launch_bounds__(256, 4) void k5b_detok(
    const float* __restrict__ x, const float* __restrict__ g2w,
    const float* __restrict__ dkw, const float* __restrict__ dkb,
    float* __restrict__ outp)
{
    __shared__ float s_dw[CF*GG];
    __shared__ float s_db[CF];
    int tid = threadIdx.x;
    int b  = blockIdx.x >> 4;
    int ck = blockIdx.x & 15;
    int l0 = (ck << 10) + (tid << 2);
    for (int i = tid; i < CF*GG; i += 256) s_dw[i] = dkw[i];
    if (tid < CF) s_db[tid] = dkb[tid];
    __syncthreads();
    float g2v[4][8];
    const float* gp = g2w + ((size_t)b*LL + l0)*GG;
    #pragma unroll
    for (int r = 0; r < 4; ++r) load8(g2v[r], gp + r*GG);
    const float* xb = x + (size_t)b*CF*LL + l0;
    float* ob = outp + (size_t)b*CF*LL + l0;
    #pragma unroll 4
    for (int c = 0; c < CF; ++c) {
        float4 xv = *(const float4*)(xb + (size_t)c*LL);
        float bias = s_db[c];
        float oa[4] = {xv.x+bias, xv.y+bias, xv.z+bias, xv.w+bias};
        #pragma unroll
        for (int g = 0; g < GG; ++g) {
            float w = s_dw[c*GG+g];
            #pragma unroll
            for (int r = 0; r < 4; ++r) oa[r] = fmaf(g2v[r][g], w, oa[r]);
        }
        *(float4*)(ob + (size_t)c*LL) = make_float4(oa[0],oa[1],oa[2],oa[3]);
    }
}

extern "C" void kernel_launch(void* const* d_in, const int* in_sizes, int n_in,
                              void* d_out, int out_size, void* d_ws, size_t ws_size,
                              hipStream_t stream) {
    const float* x       = (const float*)d_in[0];
    const float* tok_w   = (const float*)d_in[1];
    const float* tok_b   = (const float*)d_in[2];
    const float* detok_w = (const float*)d_in[3];
    const float* detok_b = (const float*)d_in[4];
    const float* ipw     = (const float*)d_in[5];
    const float* ipb     = (const float*)d_in[6];
    const float* cw      = (const float*)d_in[7];
    const float* cb      = (const float*)d_in[8];
    const float* A_log   = (const float*)d_in[9];
    const float* Dv      = (const float*)d_in[10];
    const float* dt_bias = (const float*)d_in[11];
    const float* norm_w  = (const float*)d_in[12];
    const float* out_w   = (const float*)d_in[13];
    const float* out_b   = (const float*)d_in[14];
    float* ws = (float*)d_ws;
    float* outp = (float*)d_out;

    if (ws_size < WS_FLOATS * sizeof(float)) return;

    k1a_tok<<<NB*16, 256, 0, stream>>>(x, tok_w, tok_b, ws+OFF_GT);
    k2_fused<<<NB*NGRP, 256, 0, stream>>>(ws+OFF_GT, ipw, ipb, cw, cb,
        A_log, dt_bias, Dv, ws+OFF_C, ws+OFF_YL, ws+OFF_CA,
        ws+OFF_PH, ws+OFF_CP, ws+OFF_U2, ws+OFF_AG);
    k4b_grp<<<NB, 256, 0, stream>>>(ws+OFF_U2, ws+OFF_AG, ws+OFF_GH);
    k5a_epi<<<NB*64, 256, 0, stream>>>(ws+OFF_GT, ws+OFF_C, ws+OFF_YL, ws+OFF_CA,
        ws+OFF_PH, ws+OFF_CP, ws+OFF_GH, ipw, ipb, norm_w, out_w, out_b, ws+OFF_G2);
    k5b_detok<<<NB*16, 256, 0, stream>>>(x, ws+OFF_G2, detok_w, detok_b, outp);
}